// Round 5
// baseline (395.192 us; speedup 1.0000x reference)
//
#include <hip/hip_runtime.h>

#define B_ 2
#define C_ 256
#define IC_ 128
#define N_ 4096
#define KSEL 2048

// fixed workspace offsets (floats)
#define OFF_THETA 0u
#define OFF_PHI   1048576u
#define OFF_GW    2097152u
#define OFF_GC    3145728u
#define OFF_Y     4194304u          // 2M floats
#define OFF_WEFF  6291456u
#define OFF_BEFF  6324224u
#define OFF_MEAN  6324352u
#define OFF_RSIG  6324608u
#define OFF_CNT   6324864u
#define OFF_LIST  6324928u
#define OFF_DYN   6333440u          // S (+ gc_part) start here

__device__ __forceinline__ unsigned int f2u(float f) {
    unsigned int u = __float_as_uint(f);
    return (u & 0x80000000u) ? ~u : (u | 0x80000000u);
}

// ---------------------------------------------------------------------------
// Weff[o][c] = sum_i Wgcn[i][o] * Wg[i][c];  beff[o] = sum_i Wgcn[i][o]*bg[i]
// ---------------------------------------------------------------------------
__global__ __launch_bounds__(256) void weff_kernel(
    const float* __restrict__ Wg, const float* __restrict__ bg,
    const float* __restrict__ Wgcn, float* __restrict__ Weff,
    float* __restrict__ beff)
{
    const int o = blockIdx.x, c = threadIdx.x;
    float acc = 0.f;
    for (int i = 0; i < IC_; ++i)
        acc = fmaf(Wgcn[i * IC_ + o], Wg[i * C_ + c], acc);
    Weff[o * C_ + c] = acc;
    if (c == 0) {
        float bacc = 0.f;
        for (int i = 0; i < IC_; ++i)
            bacc = fmaf(Wgcn[i * IC_ + o], bg[i], bacc);
        beff[o] = bacc;
    }
}

// ---------------------------------------------------------------------------
// Projections as tiled GEMM: {theta, gW(=Weff proj), phi} from x.
// ---------------------------------------------------------------------------
__global__ __launch_bounds__(256) void proj_kernel(
    const float* __restrict__ x,
    const float* __restrict__ Wth, const float* __restrict__ bth,
    const float* __restrict__ Weff, const float* __restrict__ beff,
    const float* __restrict__ Wph, const float* __restrict__ bph,
    float* __restrict__ theta, float* __restrict__ gW, float* __restrict__ phi)
{
    __shared__ float Xs[32][65];
    __shared__ float Ws[64][33];
    const int oc    = blockIdx.x;
    const int n0    = blockIdx.y * 64;
    const int b     = blockIdx.z;
    const int proj  = oc >> 1;
    const int orow0 = (oc & 1) * 64;
    const float* W    = (proj == 0) ? Wth : (proj == 1) ? Weff : Wph;
    const float* bias = (proj == 0) ? bth : (proj == 1) ? beff : bph;

    const int t  = threadIdx.x;
    const int tx = t & 15;
    const int ty = t >> 4;

    float acc[4][4];
#pragma unroll
    for (int u = 0; u < 4; ++u)
#pragma unroll
        for (int v = 0; v < 4; ++v) acc[u][v] = 0.f;

    const float* xb = x + (size_t)b * C_ * N_ + n0;
    for (int k0 = 0; k0 < C_; k0 += 32) {
#pragma unroll
        for (int s = 0; s < 8; ++s) {
            int e = t + 256 * s;
            int kk = e >> 6, col = e & 63;
            Xs[kk][col] = xb[(size_t)(k0 + kk) * N_ + col];
        }
#pragma unroll
        for (int s = 0; s < 8; ++s) {
            int e = t + 256 * s;
            int row = e >> 5, kk = e & 31;
            Ws[row][kk] = W[(orow0 + row) * C_ + k0 + kk];
        }
        __syncthreads();
#pragma unroll
        for (int kk = 0; kk < 32; ++kk) {
            float a[4], xv[4];
#pragma unroll
            for (int u = 0; u < 4; ++u) a[u] = Ws[ty + 16 * u][kk];
#pragma unroll
            for (int v = 0; v < 4; ++v) xv[v] = Xs[kk][tx + 16 * v];
#pragma unroll
            for (int u = 0; u < 4; ++u)
#pragma unroll
                for (int v = 0; v < 4; ++v)
                    acc[u][v] = fmaf(a[u], xv[v], acc[u][v]);
        }
        __syncthreads();
    }

#pragma unroll
    for (int u = 0; u < 4; ++u) {
        const int o = orow0 + ty + 16 * u;
        const float bo = bias[o];
#pragma unroll
        for (int v = 0; v < 4; ++v) {
            const int n = n0 + tx + 16 * v;
            const float val = acc[u][v] + bo;
            if (proj == 2) {
                phi[((size_t)b * IC_ + o) * N_ + n] = val;
            } else {
                float* dst = (proj == 0) ? theta : gW;
                dst[((size_t)b * N_ + n) * IC_ + o] = val;
            }
        }
    }
}

// ---------------------------------------------------------------------------
// hard-row compaction
// ---------------------------------------------------------------------------
__global__ __launch_bounds__(256) void compact_kernel(
    const float* __restrict__ hard_map, int* __restrict__ cnt,
    int* __restrict__ list)
{
    int idx = blockIdx.x * 256 + threadIdx.x;
    if (idx >= B_ * N_) return;
    int b = idx >> 12;
    int n = idx & (N_ - 1);
    if (hard_map[idx] > 0.5f) {
        int p = atomicAdd(&cnt[b], 1);
        list[b * N_ + p] = n;
    }
}

// ---------------------------------------------------------------------------
// score: S[lr][m] = theta[row(lr)] . phi[:,m].  Tile 64r x 128m, K chunk 64.
// grid (N/128 mtiles, qr/64 rtiles). LDS ~50KB -> 3 blocks/CU resident cap.
// ---------------------------------------------------------------------------
__global__ __launch_bounds__(256) void score_kernel(
    const float* __restrict__ theta, const float* __restrict__ phi,
    const int* __restrict__ cnt, const int* __restrict__ list,
    float* __restrict__ S, int b, int r0base)
{
    __shared__ float Th[64][65];    // [r][k]
    __shared__ float Ph[64][132];   // [k][m]
    __shared__ int sIdx[64];

    const int count = cnt[b];
    const int lr0 = blockIdx.y * 64;
    if (r0base + lr0 >= count) return;
    const int m0 = blockIdx.x * 128;
    const int t = threadIdx.x;
    const int tx = t & 15, ty = t >> 4;

    if (t < 64) {
        int gr = r0base + lr0 + t;
        sIdx[t] = (gr < count) ? list[b * N_ + gr] : -1;
    }

    float acc[4][8];
#pragma unroll
    for (int u = 0; u < 4; ++u)
#pragma unroll
        for (int v = 0; v < 8; ++v) acc[u][v] = 0.f;

    for (int kc = 0; kc < IC_; kc += 64) {
        __syncthreads();
        // Th: 64r x 64k (gathered rows)
#pragma unroll
        for (int s = 0; s < 4; ++s) {
            int e4 = t + 256 * s;           // 1024 f4: r=e4>>4, k4=e4&15
            int r = e4 >> 4, k4 = e4 & 15;
            int gr = sIdx[r];
            float4 v = make_float4(0.f, 0.f, 0.f, 0.f);
            if (gr >= 0)
                v = *(const float4*)&theta[((size_t)b * N_ + gr) * IC_ + kc + k4 * 4];
            Th[r][k4 * 4 + 0] = v.x; Th[r][k4 * 4 + 1] = v.y;
            Th[r][k4 * 4 + 2] = v.z; Th[r][k4 * 4 + 3] = v.w;
        }
        // Ph: 64k x 128m
#pragma unroll
        for (int s = 0; s < 8; ++s) {
            int e4 = t + 256 * s;           // 2048 f4: k=e4>>5, m4=e4&31
            int kk = e4 >> 5, m4 = e4 & 31;
            *(float4*)&Ph[kk][m4 * 4] =
                *(const float4*)&phi[((size_t)b * IC_ + kc + kk) * N_ + m0 + m4 * 4];
        }
        __syncthreads();

#pragma unroll 4
        for (int k = 0; k < 64; ++k) {
            float a[4];
#pragma unroll
            for (int u = 0; u < 4; ++u) a[u] = Th[ty * 4 + u][k];
            const float4 p0 = *(const float4*)&Ph[k][tx * 8];
            const float4 p1 = *(const float4*)&Ph[k][tx * 8 + 4];
            const float pm[8] = {p0.x, p0.y, p0.z, p0.w, p1.x, p1.y, p1.z, p1.w};
#pragma unroll
            for (int u = 0; u < 4; ++u)
#pragma unroll
                for (int v = 0; v < 8; ++v)
                    acc[u][v] = fmaf(a[u], pm[v], acc[u][v]);
        }
    }

#pragma unroll
    for (int u = 0; u < 4; ++u) {
        const int lr = lr0 + ty * 4 + u;
        *(float4*)&S[(size_t)lr * N_ + m0 + tx * 8] =
            make_float4(acc[u][0], acc[u][1], acc[u][2], acc[u][3]);
        *(float4*)&S[(size_t)lr * N_ + m0 + tx * 8 + 4] =
            make_float4(acc[u][4], acc[u][5], acc[u][6], acc[u][7]);
    }
}

// ---------------------------------------------------------------------------
// select: per-row exact kth-largest radix select + softmax; writes P in-place
// into S (selected: exp(s-m)*inv, else 0). grid qr blocks.
// ---------------------------------------------------------------------------
__global__ __launch_bounds__(256) void select_kernel(
    float* __restrict__ S, const int* __restrict__ cnt, int b, int r0base)
{
    __shared__ unsigned int sHist[4][256];
    __shared__ unsigned int sWsum[4];
    __shared__ float sRed[8];
    __shared__ unsigned long long sPrefix;
    __shared__ unsigned int sRemain;

    const int lr = blockIdx.x;
    if (r0base + lr >= cnt[b]) return;
    const int t = threadIdx.x, lane = t & 63, wid = t >> 6;

    float4* row = (float4*)(S + (size_t)lr * N_);
    float4 v[4];
#pragma unroll
    for (int q = 0; q < 4; ++q) v[q] = row[t + 256 * q];

    float m = -3.4e38f;
#pragma unroll
    for (int q = 0; q < 4; ++q)
        m = fmaxf(m, fmaxf(fmaxf(v[q].x, v[q].y), fmaxf(v[q].z, v[q].w)));
#pragma unroll
    for (int off = 32; off > 0; off >>= 1) m = fmaxf(m, __shfl_xor(m, off));
    if (lane == 0) sRed[wid] = m;
    __syncthreads();
    m = fmaxf(fmaxf(sRed[0], sRed[1]), fmaxf(sRed[2], sRed[3]));

    unsigned long long prefix = 0ull;
    unsigned int remain = KSEL;
    for (int d = 3; d >= 0; --d) {
        __syncthreads();
#pragma unroll
        for (int w = 0; w < 4; ++w) sHist[w][t] = 0u;
        __syncthreads();
        const float* pv = (const float*)v;
#pragma unroll
        for (int e = 0; e < 16; ++e) {
            unsigned int u = f2u(pv[e]);
            if ((((unsigned long long)u) >> (8 * (d + 1))) == prefix)
                atomicAdd(&sHist[wid][(u >> (8 * d)) & 255u], 1u);
        }
        __syncthreads();
        unsigned int x = sHist[0][t] + sHist[1][t] + sHist[2][t] + sHist[3][t];
        unsigned int own = x;
#pragma unroll
        for (int off = 1; off < 64; off <<= 1) {
            unsigned int y = __shfl_down(x, off);
            if (lane + off < 64) x += y;
        }
        if (lane == 0) sWsum[wid] = x;
        __syncthreads();
        for (int w = wid + 1; w < 4; ++w) x += sWsum[w];
        unsigned int nxt = x - own;        // suffix starting at t+1
        if (x >= remain && nxt < remain) {
            sPrefix = (prefix << 8) | (unsigned long long)t;
            sRemain = remain - nxt;
        }
        __syncthreads();
        prefix = sPrefix;
        remain = sRemain;
    }
    const unsigned int tu = (unsigned int)prefix;

    float z = 0.f, ssel = 0.f;
    const float* pv = (const float*)v;
#pragma unroll
    for (int e = 0; e < 16; ++e) {
        float val = pv[e];
        float ex = expf(val - m);
        z += ex;
        if (f2u(val) >= tu) ssel += ex;
    }
#pragma unroll
    for (int off = 32; off > 0; off >>= 1) {
        z    += __shfl_xor(z, off);
        ssel += __shfl_xor(ssel, off);
    }
    __syncthreads();
    if (lane == 0) { sRed[wid] = z; sRed[4 + wid] = ssel; }
    __syncthreads();
    const float zt = sRed[0] + sRed[1] + sRed[2] + sRed[3];
    const float st = sRed[4] + sRed[5] + sRed[6] + sRed[7];
    const float inv = 1.f / (st + 1e-6f * zt);

    // write P in place
#pragma unroll
    for (int q = 0; q < 4; ++q) {
        float* c = (float*)&v[q];
        float4 p;
        float* pp = (float*)&p;
#pragma unroll
        for (int e = 0; e < 4; ++e)
            pp[e] = (f2u(c[e]) >= tu) ? expf(c[e] - m) * inv : 0.f;
        row[t + 256 * q] = p;
    }
}

// ---------------------------------------------------------------------------
// pv: pure split-K GEMM gc_part[ks][lr][i] = sum_{j in ks*256..} P[lr][j]*gW[j][i]
// grid (qr/64, 16). Tile 64r x 128i, j chunk 64.
// ---------------------------------------------------------------------------
__global__ __launch_bounds__(256) void pv_kernel(
    const float* __restrict__ S, const float* __restrict__ gW,
    const int* __restrict__ cnt, float* __restrict__ gc_part,
    int b, int r0base, int qr)
{
    __shared__ float Pt[64][65];     // [r][j]
    __shared__ float Ws[64][132];    // [j][i]

    const int count = cnt[b];
    const int lr0 = blockIdx.x * 64;
    if (r0base + lr0 >= count) return;
    const int ks = blockIdx.y;
    const int t = threadIdx.x;
    const int tx = t & 15, ty = t >> 4;

    float acc[4][8];
#pragma unroll
    for (int u = 0; u < 4; ++u)
#pragma unroll
        for (int v = 0; v < 8; ++v) acc[u][v] = 0.f;

    for (int jc = ks * 256; jc < ks * 256 + 256; jc += 64) {
        __syncthreads();
        // Pt: 64r x 64j from S (already transformed to P)
#pragma unroll
        for (int s = 0; s < 4; ++s) {
            int e4 = t + 256 * s;
            int r = e4 >> 4, j4 = e4 & 15;
            float4 p = *(const float4*)&S[(size_t)(lr0 + r) * N_ + jc + j4 * 4];
            Pt[r][j4 * 4 + 0] = p.x; Pt[r][j4 * 4 + 1] = p.y;
            Pt[r][j4 * 4 + 2] = p.z; Pt[r][j4 * 4 + 3] = p.w;
        }
        // Ws: 64j x 128i
#pragma unroll
        for (int s = 0; s < 8; ++s) {
            int e4 = t + 256 * s;
            int jj = e4 >> 5, i4 = e4 & 31;
            *(float4*)&Ws[jj][i4 * 4] =
                *(const float4*)&gW[((size_t)b * N_ + jc + jj) * IC_ + i4 * 4];
        }
        __syncthreads();

#pragma unroll 4
        for (int j = 0; j < 64; ++j) {
            float a[4];
#pragma unroll
            for (int u = 0; u < 4; ++u) a[u] = Pt[ty * 4 + u][j];
            const float4 w0 = *(const float4*)&Ws[j][tx * 8];
            const float4 w1 = *(const float4*)&Ws[j][tx * 8 + 4];
            const float wm[8] = {w0.x, w0.y, w0.z, w0.w, w1.x, w1.y, w1.z, w1.w};
#pragma unroll
            for (int u = 0; u < 4; ++u)
#pragma unroll
                for (int v = 0; v < 8; ++v)
                    acc[u][v] = fmaf(a[u], wm[v], acc[u][v]);
        }
    }

#pragma unroll
    for (int u = 0; u < 4; ++u) {
        const int lr = lr0 + ty * 4 + u;
        *(float4*)&gc_part[((size_t)ks * qr + lr) * IC_ + tx * 8] =
            make_float4(acc[u][0], acc[u][1], acc[u][2], acc[u][3]);
        *(float4*)&gc_part[((size_t)ks * qr + lr) * IC_ + tx * 8 + 4] =
            make_float4(acc[u][4], acc[u][5], acc[u][6], acc[u][7]);
    }
}

// ---------------------------------------------------------------------------
// reduce split-K partials, ReLU, scatter to gc[b][n][i]
// ---------------------------------------------------------------------------
__global__ __launch_bounds__(256) void scatter_kernel(
    const float* __restrict__ gc_part, const int* __restrict__ cnt,
    const int* __restrict__ list, float* __restrict__ gc,
    int b, int r0base, int qr)
{
    int idx = blockIdx.x * 256 + threadIdx.x;
    int lr = idx >> 7, i = idx & 127;
    if (r0base + lr >= cnt[b]) return;
    float v = 0.f;
#pragma unroll
    for (int ks = 0; ks < 16; ++ks)
        v += gc_part[((size_t)ks * qr + lr) * IC_ + i];
    int n = list[b * N_ + r0base + lr];
    gc[((size_t)b * N_ + n) * IC_ + i] = fmaxf(v, 0.f);
}

// ---------------------------------------------------------------------------
// y[b,c,n] = Wout[c,:] . gc[b,n,:] + bout[c].  Tile 64c x 64n, K chunk 32.
// grid (N/64, C/64, B) = 512 blocks, acc 4x4/thread.
// ---------------------------------------------------------------------------
__global__ __launch_bounds__(256) void y_kernel(
    const float* __restrict__ gc, const float* __restrict__ Wout,
    const float* __restrict__ bout, float* __restrict__ y)
{
    __shared__ float Wt[64][33];   // [c][k]
    __shared__ float Gt[32][68];   // [k][n]
    const int n0 = blockIdx.x * 64;
    const int c0 = blockIdx.y * 64;
    const int b  = blockIdx.z;
    const int t = threadIdx.x;
    const int tx = t & 15, ty = t >> 4;

    float acc[4][4];
#pragma unroll
    for (int u = 0; u < 4; ++u)
#pragma unroll
        for (int v = 0; v < 4; ++v) acc[u][v] = 0.f;

    for (int kc = 0; kc < IC_; kc += 32) {
        __syncthreads();
        // Wt: 64c x 32k
#pragma unroll
        for (int s = 0; s < 2; ++s) {
            int e4 = t + 256 * s;            // 512 f4: c=e4>>3, k4=e4&7
            int c = e4 >> 3, k4 = e4 & 7;
            float4 w = *(const float4*)&Wout[(size_t)(c0 + c) * IC_ + kc + k4 * 4];
            Wt[c][k4 * 4 + 0] = w.x; Wt[c][k4 * 4 + 1] = w.y;
            Wt[c][k4 * 4 + 2] = w.z; Wt[c][k4 * 4 + 3] = w.w;
        }
        // Gt: 32k x 64n (transposed from gc [n][i])
#pragma unroll
        for (int s = 0; s < 2; ++s) {
            int e4 = t + 256 * s;            // 512 f4: nn=e4>>3, k4=e4&7
            int nn = e4 >> 3, k4 = e4 & 7;
            float4 g = *(const float4*)&gc[((size_t)b * N_ + n0 + nn) * IC_ + kc + k4 * 4];
            Gt[k4 * 4 + 0][nn] = g.x; Gt[k4 * 4 + 1][nn] = g.y;
            Gt[k4 * 4 + 2][nn] = g.z; Gt[k4 * 4 + 3][nn] = g.w;
        }
        __syncthreads();

#pragma unroll 4
        for (int k = 0; k < 32; ++k) {
            float a[4];
#pragma unroll
            for (int u = 0; u < 4; ++u) a[u] = Wt[ty * 4 + u][k];
            const float4 g4 = *(const float4*)&Gt[k][tx * 4];
            const float gm[4] = {g4.x, g4.y, g4.z, g4.w};
#pragma unroll
            for (int u = 0; u < 4; ++u)
#pragma unroll
                for (int v = 0; v < 4; ++v)
                    acc[u][v] = fmaf(a[u], gm[v], acc[u][v]);
        }
    }

#pragma unroll
    for (int u = 0; u < 4; ++u) {
        const int c = c0 + ty * 4 + u;
        const float bo = bout[c];
        *(float4*)&y[((size_t)b * C_ + c) * N_ + n0 + tx * 4] =
            make_float4(acc[u][0] + bo, acc[u][1] + bo,
                        acc[u][2] + bo, acc[u][3] + bo);
    }
}

// ---------------------------------------------------------------------------
// BatchNorm stats per channel
// ---------------------------------------------------------------------------
__global__ __launch_bounds__(256) void bn_stats_kernel(
    const float* __restrict__ y, float* __restrict__ mean,
    float* __restrict__ rsig)
{
    __shared__ float sr[8];
    const int c = blockIdx.x, t = threadIdx.x;
    const int lane = t & 63, wid = t >> 6;
    float s = 0.f, ss = 0.f;
    for (int b = 0; b < B_; ++b) {
        const float* yr = y + ((size_t)b * C_ + c) * N_;
        for (int n = t; n < N_; n += 256) {
            float v = yr[n];
            s += v; ss = fmaf(v, v, ss);
        }
    }
#pragma unroll
    for (int off = 32; off > 0; off >>= 1) {
        s  += __shfl_xor(s, off);
        ss += __shfl_xor(ss, off);
    }
    if (lane == 0) { sr[wid] = s; sr[4 + wid] = ss; }
    __syncthreads();
    if (t == 0) {
        float st  = sr[0] + sr[1] + sr[2] + sr[3];
        float sst = sr[4] + sr[5] + sr[6] + sr[7];
        float mu  = st / (float)(B_ * N_);
        float var = sst / (float)(B_ * N_) - mu * mu;
        mean[c] = mu;
        rsig[c] = rsqrtf(var + 1e-5f);
    }
}

// ---------------------------------------------------------------------------
// out = x + gamma*(y-mean)*rsig + beta
// ---------------------------------------------------------------------------
__global__ __launch_bounds__(256) void final_kernel(
    const float* __restrict__ x, const float* __restrict__ y,
    const float* __restrict__ mean, const float* __restrict__ rsig,
    const float* __restrict__ gamma, const float* __restrict__ beta,
    float* __restrict__ out)
{
    int idx = blockIdx.x * 256 + threadIdx.x;
    if (idx >= B_ * C_ * N_) return;
    int c = (idx >> 12) & (C_ - 1);
    out[idx] = x[idx] + fmaf(gamma[c], (y[idx] - mean[c]) * rsig[c], beta[c]);
}

extern "C" void kernel_launch(void* const* d_in, const int* in_sizes, int n_in,
                              void* d_out, int out_size, void* d_ws, size_t ws_size,
                              hipStream_t stream)
{
    const float* x     = (const float*)d_in[0];
    const float* hard  = (const float*)d_in[1];
    const float* Wg    = (const float*)d_in[2];
    const float* bg    = (const float*)d_in[3];
    const float* Wth   = (const float*)d_in[4];
    const float* bth   = (const float*)d_in[5];
    const float* Wph   = (const float*)d_in[6];
    const float* bph   = (const float*)d_in[7];
    const float* Wgcn  = (const float*)d_in[8];
    const float* Wout  = (const float*)d_in[9];
    const float* bout  = (const float*)d_in[10];
    const float* gamma = (const float*)d_in[11];
    const float* beta  = (const float*)d_in[12];
    float* out = (float*)d_out;
    float* ws  = (float*)d_ws;

    float* theta = ws + OFF_THETA;
    float* phi   = ws + OFF_PHI;
    float* gW    = ws + OFF_GW;
    float* gc    = ws + OFF_GC;
    float* y     = ws + OFF_Y;
    float* Weff  = ws + OFF_WEFF;
    float* beff  = ws + OFF_BEFF;
    float* mean  = ws + OFF_MEAN;
    float* rsig  = ws + OFF_RSIG;
    int*   cnt   = (int*)(ws + OFF_CNT);
    int*   list  = (int*)(ws + OFF_LIST);

    // runtime-adaptive row-block size: pick largest that fits the workspace
    const size_t wsf = ws_size / sizeof(float);
    int qr = 1024;
    if (wsf >= OFF_DYN + 25165824u)       qr = 4096;  // S 16M + gc_part 8M
    else if (wsf >= OFF_DYN + 12582912u)  qr = 2048;  // S 8M  + gc_part 4M
    float* S = ws + OFF_DYN;
    float* gc_part = (qr == 1024) ? out : S + (size_t)qr * N_;
    // (qr==1024: d_out (2M floats) used as split-K scratch, fully overwritten
    //  by final_kernel at the end.)

    hipMemsetAsync(cnt, 0, 2 * sizeof(int), stream);
    hipMemsetAsync(gc, 0, (size_t)B_ * N_ * IC_ * sizeof(float), stream);

    weff_kernel<<<dim3(IC_), 256, 0, stream>>>(Wg, bg, Wgcn, Weff, beff);
    proj_kernel<<<dim3(6, N_ / 64, B_), 256, 0, stream>>>(
        x, Wth, bth, Weff, beff, Wph, bph, theta, gW, phi);
    compact_kernel<<<dim3(B_ * N_ / 256), 256, 0, stream>>>(hard, cnt, list);

    for (int b = 0; b < B_; ++b) {
        for (int r0 = 0; r0 < N_; r0 += qr) {
            score_kernel<<<dim3(N_ / 128, qr / 64), 256, 0, stream>>>(
                theta, phi, cnt, list, S, b, r0);
            select_kernel<<<dim3(qr), 256, 0, stream>>>(S, cnt, b, r0);
            pv_kernel<<<dim3(qr / 64, 16), 256, 0, stream>>>(
                S, gW, cnt, gc_part, b, r0, qr);
            scatter_kernel<<<dim3(qr / 2), 256, 0, stream>>>(
                gc_part, cnt, list, gc, b, r0, qr);
        }
    }

    y_kernel<<<dim3(N_ / 64, C_ / 64, B_), 256, 0, stream>>>(gc, Wout, bout, y);
    bn_stats_kernel<<<dim3(C_), 256, 0, stream>>>(y, mean, rsig);
    final_kernel<<<dim3(B_ * C_ * N_ / 256), 256, 0, stream>>>(
        x, y, mean, rsig, gamma, beta, out);
}